// Round 1
// baseline (628.323 us; speedup 1.0000x reference)
//
#include <hip/hip_runtime.h>

#define CH 64   // IN_CH == OUT_CH == 64

// HW fp32 atomic add (global_atomic_add_f32 on gfx950)
__device__ inline void atomic_add_f32(float* p, float v) {
    unsafeAtomicAdd(p, v);
}

// One wave (64 lanes) per edge; lane = channel.
// G[row][lane] += a * x[col][lane];  Sa[row] += a;  cnt[row] += 1
__global__ __launch_bounds__(256) void edge_scatter_kernel(
    const int* __restrict__ ei,      // [2, E] flat: row = ei[e], col = ei[E+e]
    const float* __restrict__ attr,  // [E]
    const float* __restrict__ x,     // [N, 64]
    float* __restrict__ G,           // [N, 64] accumulators (pre-zeroed)
    float* __restrict__ Sa,          // [N]
    float* __restrict__ cnt,         // [N]
    int E)
{
    int wid  = (blockIdx.x * blockDim.x + threadIdx.x) >> 6;  // edge id
    int lane = threadIdx.x & 63;
    if (wid >= E) return;

    int   row = ei[wid];
    int   col = ei[E + wid];
    float a   = attr[wid];

    float xv = x[(size_t)col * CH + lane];
    atomic_add_f32(&G[(size_t)row * CH + lane], a * xv);

    if (lane == 0)      atomic_add_f32(&Sa[row], a);
    else if (lane == 1) atomic_add_f32(&cnt[row], 1.0f);
}

// out[n][o] = (Sa[n] * (x[n] @ W1)[o] + (G[n] @ W2)[o]) / max(cnt[n],1) + bias[o]
// W1 = weight rows [0,64), W2 = weight rows [64,128). weight is [128,64] row-major.
__global__ __launch_bounds__(256) void node_out_kernel(
    const float* __restrict__ x,
    const float* __restrict__ G,
    const float* __restrict__ Sa,
    const float* __restrict__ cnt,
    const float* __restrict__ W,     // [128, 64]
    const float* __restrict__ bias,  // [64]
    float* __restrict__ out,         // [N, 64]
    int N)
{
    __shared__ float Wl[128 * CH];       // 32 KB
    __shared__ float xr[4][CH];
    __shared__ float gr[4][CH];

    for (int i = threadIdx.x; i < 128 * CH; i += 256)
        Wl[i] = W[i];

    int sub = threadIdx.x >> 6;          // 0..3 : node within block
    int o   = threadIdx.x & 63;          // output channel
    int n   = blockIdx.x * 4 + sub;

    if (n < N) {
        xr[sub][o] = x[(size_t)n * CH + o];
        gr[sub][o] = G[(size_t)n * CH + o];
    }
    __syncthreads();
    if (n >= N) return;

    float acc1 = 0.0f, acc2 = 0.0f;
    #pragma unroll
    for (int k = 0; k < CH; ++k) {
        acc1 += xr[sub][k] * Wl[k * CH + o];          // x @ W1
        acc2 += gr[sub][k] * Wl[(64 + k) * CH + o];   // G @ W2
    }

    float c = cnt[n];
    c = c > 1.0f ? c : 1.0f;
    out[(size_t)n * CH + o] = (Sa[n] * acc1 + acc2) / c + bias[o];
}

extern "C" void kernel_launch(void* const* d_in, const int* in_sizes, int n_in,
                              void* d_out, int out_size, void* d_ws, size_t ws_size,
                              hipStream_t stream) {
    const float* x    = (const float*)d_in[0];   // [N, 64] f32
    const int*   ei   = (const int*)d_in[1];     // [2, E] int
    const float* attr = (const float*)d_in[2];   // [E] f32
    const float* W    = (const float*)d_in[3];   // [128, 64] f32
    const float* bias = (const float*)d_in[4];   // [64] f32
    float*       out  = (float*)d_out;           // [N, 64] f32

    int N = in_sizes[0] / CH;     // 50000
    int E = in_sizes[2];          // 1,600,000

    float* G   = (float*)d_ws;            // [N,64]
    float* Sa  = G + (size_t)N * CH;      // [N]
    float* cnt = Sa + N;                  // [N]

    size_t zero_bytes = ((size_t)N * CH + 2 * (size_t)N) * sizeof(float);
    hipMemsetAsync(d_ws, 0, zero_bytes, stream);

    // one wave per edge
    long long total_threads = (long long)E * 64;
    int blocks = (int)((total_threads + 255) / 256);
    edge_scatter_kernel<<<blocks, 256, 0, stream>>>(ei, attr, x, G, Sa, cnt, E);

    node_out_kernel<<<(N + 3) / 4, 256, 0, stream>>>(x, G, Sa, cnt, W, bias, out, N);
}